// Round 23
// baseline (48.173 us; speedup 1.0000x reference)
//
#include <hip/hip_runtime.h>
#include <math.h>

#define B_    8
#define C_    128
#define L_    8192
#define O_    128
#define POS_  10
#define CHIN  798
#define CH_   266          // 128 direct + 128 gathered + 10 penc
#define GS    288          // G row stride (all channels materialized)
#define NCH   9            // chunks of 32 channels
#define TL2   256          // l-tile for GEMM (256 blocks, wave tile 64o x 128l)
#define G_ELEMS  ((size_t)B_ * L_ * GS)       // f16: 37.75 MB
#define WT_ELEMS ((size_t)3 * NCH * O_ * 32)  // f16: 221 KB

typedef _Float16 half8 __attribute__((ext_vector_type(8)));
typedef short short8 __attribute__((ext_vector_type(8)));
typedef float f32x4  __attribute__((ext_vector_type(4)));

typedef __attribute__((address_space(3))) unsigned       lds_uint;
typedef __attribute__((address_space(1))) const unsigned gl_uint;

// direct global->LDS DMA, 16B per lane; LDS dest is wave-uniform base + lane*16
__device__ __forceinline__ void dma16(const _Float16* g, _Float16* l) {
    __builtin_amdgcn_global_load_lds((gl_uint*)g, (lds_uint*)l, 16, 0, 0);
}

// ---------------------------------------------------------------------------
// mask dtype detect core: 256 threads scan 64 KB; mflag 1=byte,0=i32,2=i64
// ---------------------------------------------------------------------------
__device__ __forceinline__ void detect_core(const uint4* __restrict__ m,
                                            int* __restrict__ mflag, int tid) {
    __shared__ int s[2];
    if (tid < 2) s[tid] = 0;
    __syncthreads();
    unsigned sub = 0, mid = 0;
    #pragma unroll
    for (int k = 0; k < 16; ++k) {
        uint4 w = m[tid + k * 256];              // 4096 * 16B = 64 KB
        sub |= (w.x | w.y | w.z | w.w) & 0xFFFFFF00u;
        mid |= (w.y | w.w) & 0x000000FFu;
    }
    unsigned long long bs = __ballot(sub != 0);
    unsigned long long bm = __ballot(mid != 0);
    if ((tid & 63) == 0) {
        if (bs) atomicOr(&s[0], 1);
        if (bm) atomicOr(&s[1], 1);
    }
    __syncthreads();
    if (tid == 0) mflag[0] = s[0] ? 1 : (s[1] ? 0 : 2);
}

__global__ void detect_kernel(const uint4* __restrict__ m, int* __restrict__ mflag) {
    detect_core(m, mflag, threadIdx.x);
}

// ---------------------------------------------------------------------------
// prep: blocks [0,2048): transpose inputs[b,c,l] f32 -> G[b,l,c] f16 (c<128)
//       blocks [2048,2480): Wt2[t][ch][o][cc] = (f16) W[o][3*(ch*32+cc)+t]
//       block 2480: mask dtype detect
// ---------------------------------------------------------------------------
__global__ __launch_bounds__(256, 4)
void prep_kernel(const float* __restrict__ inputs, const float* __restrict__ W,
                 const uint4* __restrict__ maskv,
                 _Float16* __restrict__ G, _Float16* __restrict__ Wt2,
                 int* __restrict__ mflag) {
    __shared__ float tile[64][65];
    const int bid = blockIdx.x;
    const int tid = threadIdx.x;

    if (bid == 2480) { detect_core(maskv, mflag, tid); return; }

    if (bid >= 2048) {   // Wt2 prep: 432 blocks * 256 = 110,592 elems exact
        int idx = (bid - 2048) * 256 + tid;
        int cc  = idx & 31;
        int o   = (idx >> 5) & 127;
        int tch = idx >> 12;          // 0..26
        int ch  = tch % 9;
        int t   = tch / 9;
        int cg  = ch * 32 + cc;
        Wt2[idx] = (cg < CH_) ? (_Float16)W[o * CHIN + 3 * cg + t] : (_Float16)0.f;
        return;
    }

    const int b  = bid & 7;          // b -> XCD affinity
    const int r  = bid >> 3;
    const int c0 = (r & 1) * 64;
    const int l0 = (r >> 1) * 64;
    const int ty = tid >> 6, tx = tid & 63;

    #pragma unroll
    for (int it = 0; it < 16; ++it) {
        int cl = it * 4 + ty;
        tile[cl][tx] = inputs[((size_t)(b * C_ + c0 + cl)) * L_ + l0 + tx];
    }
    __syncthreads();
    const int cp = (tid & 31) * 2;
    const int lr = tid >> 5;          // 0..7
    #pragma unroll
    for (int it = 0; it < 8; ++it) {
        int ll = it * 8 + lr;
        _Float16 pair[2] = {(_Float16)tile[cp][ll], (_Float16)tile[cp + 1][ll]};
        *(unsigned*)&G[((size_t)(b * L_ + l0 + ll)) * GS + c0 + cp] = *(unsigned*)pair;
    }
}

// ---------------------------------------------------------------------------
// K1: gather + penc into G (coalesced; uint4/lane -> 256B per 16-lane row):
//   G[b,l,128+c] = G[b,conn[b,l],c]  (c<128) ; G[b,l,256+p] = penc (p<32)
// ---------------------------------------------------------------------------
__global__ __launch_bounds__(256, 4)
void k1_gather_penc(const int* __restrict__ conn, _Float16* __restrict__ G) {
    const int bid = blockIdx.x;
    const int b  = bid & 7;
    const int l0 = (bid >> 3) * 64;
    const int tid = threadIdx.x;
    const int wv = tid >> 6, lane = tid & 63;

    // gather: 4 rows per wave-iter; 16B/lane x 16 lanes = 256B per row
    #pragma unroll
    for (int i = 0; i < 4; ++i) {
        int l  = l0 + wv * 16 + i * 4 + (lane >> 4);
        int cj = conn[b * L_ + l];
        uint4 v = *(const uint4*)&G[((size_t)(b * L_ + cj)) * GS + (lane & 15) * 8];
        *(uint4*)&G[((size_t)(b * L_ + l)) * GS + 128 + (lane & 15) * 8] = v;
    }

    // penc: thread -> (l, 8-wide c' group); channels 256..287 (zeros past 265)
    {
        int l = l0 + (tid >> 2);
        int s = tid & 3;
        int cj = conn[b * L_ + l];
        float d = (float)(l - cj);
        _Float16 v[8];
        #pragma unroll
        for (int e = 0; e < 8; ++e) {
            int p = s * 8 + e;
            if (p < POS_) {
                float sc = (float)(1 << p);
                v[e] = (_Float16)sinf((sc * d) / 1000.0f);
            } else v[e] = (_Float16)0.f;
        }
        *(short8*)&G[((size_t)(b * L_ + l)) * GS + 256 + s * 8] = *(short8*)v;
    }
}

// ---------------------------------------------------------------------------
// K2: f16 MFMA GEMM, all-contiguous global_load_lds staging.
// TL2=256: grid 256 flat (b=bid&7 -> XCD), 256 thr = 4 waves (2o x 2l),
// wave tile 64o x 128l (acc[4][8], 128 VGPR) -> 25% fewer LDS reads/output,
// A-DMA and barrier drains amortized over 2x outputs.
// A single-buffered (24.6 KB); B double-buffered (2x258x32, 32.3 KB);
// LDS 57 KB -> 2 blocks/CU. 2 barriers/chunk. Halo rows 0/257 reg-staged.
// ---------------------------------------------------------------------------
__global__ __launch_bounds__(256)
void k2_gemm(const _Float16* __restrict__ G, const _Float16* __restrict__ Wt2,
             const unsigned char* __restrict__ mask,
             const float* __restrict__ bias,
             float* __restrict__ out,
             const int* __restrict__ mflag_p) {
    __shared__ _Float16 As[3][128][32];     // 24.6 KB [tap][o][c]
    __shared__ _Float16 Bs[2][258][32];     // 32.3 KB [buf][row][c]

    const int bid = blockIdx.x;           // 0..255
    const int b   = bid & 7;
    const int l0  = (bid >> 3) * TL2;
    const int tid  = threadIdx.x;
    const int wave = tid >> 6;            // 0..3
    const int lane = tid & 63;
    const int wo = wave & 1;              // o-half (64)
    const int wl = wave >> 1;             // l-half (128)
    const int g  = lane >> 4;
    const int ln = lane & 15;

    const _Float16* gb = G + (size_t)b * L_ * GS;
    const int cbl = lane & 3;             // 16B slot within 64B row segment

    auto stage_A = [&](int ch) {
        #pragma unroll
        for (int i = 0; i < 6; ++i) {
            int ap = 6 * wave + i;        // 0..23
            int tp = ap >> 3;             // 0..2
            int og = ap & 7;              // o block of 16
            int o  = og * 16 + (lane >> 2);
            dma16(&Wt2[((size_t)((tp * NCH + ch) * O_ + o)) * 32 + cbl * 8],
                  &As[tp][og * 16][0]);
        }
    };
    auto stage_B = [&](int ch, int buf) {
        #pragma unroll
        for (int i = 0; i < 4; ++i) {
            int r0 = 1 + 64 * wave + 16 * i;
            int r  = r0 + (lane >> 2);    // rows 1..256 -> l in [l0, l0+255]
            dma16(&gb[(size_t)(l0 - 1 + r) * GS + ch * 32 + cbl * 8],
                  &Bs[buf][r0][0]);
        }
    };

    // halo rows 0 and 257 (l = l0-1, l0+256): 8 threads reg-stage
    auto halo_load = [&](int ch) -> short8 {
        int row = (tid >> 2) ? 257 : 0;
        int l_  = l0 - 1 + row;
        short8 v = (short8)0;
        if ((unsigned)l_ < (unsigned)L_)
            v = *(const short8*)&gb[(size_t)l_ * GS + ch * 32 + (tid & 3) * 8];
        return v;
    };
    auto halo_write = [&](short8 v, int buf) {
        int row = (tid >> 2) ? 257 : 0;
        *(short8*)&Bs[buf][row][(tid & 3) * 8] = v;
    };

#define COMPUTE(BUF) { _Pragma("unroll") for (int t_ = 0; t_ < 3; ++t_) { \
        half8 bf_[8]; \
        _Pragma("unroll") for (int n_ = 0; n_ < 8; ++n_) \
            bf_[n_] = *(const half8*)&Bs[BUF][wl * 128 + n_ * 16 + ln + t_][8 * g]; \
        _Pragma("unroll") for (int m_ = 0; m_ < 4; ++m_) { \
            half8 af_ = *(const half8*)&As[t_][wo * 64 + m_ * 16 + ln][8 * g]; \
            _Pragma("unroll") for (int n_ = 0; n_ < 8; ++n_) \
                acc[m_][n_] = __builtin_amdgcn_mfma_f32_16x16x32_f16(af_, bf_[n_], acc[m_][n_], 0, 0, 0); } } }

    f32x4 acc[4][8];
    #pragma unroll
    for (int m = 0; m < 4; ++m)
        #pragma unroll
        for (int n = 0; n < 8; ++n) acc[m][n] = (f32x4)0.f;

    short8 hv;

    // prologue: stage chunk 0 (A + B into buf 0)
    stage_A(0);
    stage_B(0, 0);
    if (tid < 8) { hv = halo_load(0); halo_write(hv, 0); }
    __syncthreads();   // vmcnt(0) drain before barrier

    int cur = 0;
    for (int ch = 0; ch < NCH; ++ch) {
        const bool more = (ch + 1 < NCH);
        if (more) {
            stage_B(ch + 1, cur ^ 1);      // overlaps with compute below
            if (tid < 8) hv = halo_load(ch + 1);
        }
        COMPUTE(cur);
        if (more) {
            __syncthreads();               // all waves done reading As
            stage_A(ch + 1);               // single-buffer A reload
            if (tid < 8) halo_write(hv, cur ^ 1);
            __syncthreads();               // drain A-DMA; publish halo
            cur ^= 1;
        }
    }

    // epilogue: D col = lane&15 (l), row = g*4+r (o) within frag
    const int mflag = mflag_p[0];
    #pragma unroll
    for (int n = 0; n < 8; ++n) {
        int l = l0 + wl * 128 + n * 16 + ln;
        int idx = b * L_ + l;
        float mv;
        if (mflag == 1)      mv = mask[idx] ? 1.f : 0.f;
        else if (mflag == 0) mv = ((const int*)mask)[idx] ? 1.f : 0.f;
        else                 mv = ((const int*)mask)[2 * idx] ? 1.f : 0.f;
        #pragma unroll
        for (int m = 0; m < 4; ++m) {
            #pragma unroll
            for (int r = 0; r < 4; ++r) {
                int o = wo * 64 + m * 16 + g * 4 + r;
                out[((size_t)(b * O_ + o)) * L_ + l] = (acc[m][n][r] + bias[o]) * mv;
            }
        }
    }
#undef COMPUTE
}

// ---------------------------------------------------------------------------
// Fallback (fp32 vector path) if workspace too small
// ---------------------------------------------------------------------------
__global__ __launch_bounds__(256, 2)
void cc_fallback_kernel(const float* __restrict__ inputs,
                        const int* __restrict__ conn,
                        const unsigned char* __restrict__ mask,
                        const float* __restrict__ W,
                        const float* __restrict__ bias,
                        float* __restrict__ out,
                        const int* __restrict__ mflag_p) {
    __shared__ int   conn_s[130];
    __shared__ float feat_s[16][132];
    __shared__ float Ws[48][136];

    const int b   = blockIdx.y;
    const int l0  = blockIdx.x * 128;
    const int tid = threadIdx.x;
    const int ot  = tid >> 4;
    const int lt  = tid & 15;
    const int o0  = ot * 8;
    const int ll  = lt * 8;

    for (int j = tid; j < 130; j += 256) {
        int lg = l0 - 1 + j;
        conn_s[j] = ((unsigned)lg < (unsigned)L_) ? conn[b * L_ + lg] : -1;
    }
    float acc[8][8];
    #pragma unroll
    for (int i = 0; i < 8; ++i)
        #pragma unroll
        for (int j = 0; j < 8; ++j) acc[i][j] = 0.f;

    const int tc = ot, tj = lt;
    for (int chunk = 0; chunk < 17; ++chunk) {
        const int CN  = (chunk < 16) ? 16 : POS_;
        const int cg0 = chunk * 16;
        const int col0 = 3 * cg0;
        __syncthreads();
        {
            const int nw = O_ * CN * 3;
            for (int idx = tid; idx < nw; idx += 256) {
                int o = idx & 127, kk = idx >> 7;
                Ws[kk][o] = W[o * CHIN + col0 + kk];
            }
        }
        if (chunk < 8) {
            const float* src = inputs + ((size_t)b * C_ + (cg0 + tc)) * L_;
            for (int j = tj; j < 130; j += 16) {
                int lg = l0 - 1 + j;
                feat_s[tc][j] = ((unsigned)lg < (unsigned)L_) ? src[lg] : 0.f;
            }
        } else if (chunk < 16) {
            const float* src = inputs + ((size_t)b * C_ + (cg0 - 128 + tc)) * L_;
            for (int j = tj; j < 130; j += 16) {
                int cj = conn_s[j];
                feat_s[tc][j] = (cj >= 0) ? src[cj] : 0.f;
            }
        } else if (tc < POS_) {
            const float sc = (float)(1 << tc);
            for (int j = tj; j < 130; j += 16) {
                int cj = conn_s[j];
                int lg = l0 - 1 + j;
                float v = 0.f;
                if (cj >= 0) v = sinf((sc * (float)(lg - cj)) / 1000.0f);
                feat_s[tc][j] = v;
            }
        }
        __syncthreads();
        for (int c = 0; c < CN; ++c) {
            float f[10];
            float4 fa = *(const float4*)&feat_s[c][ll];
            float4 fb = *(const float4*)&feat_s[c][ll + 4];
            float2 fc2 = *(const float2*)&feat_s[c][ll + 8];
            f[0]=fa.x; f[1]=fa.y; f[2]=fa.z; f[3]=fa.w;
            f[4]=fb.x; f[5]=fb.y; f[6]=fb.z; f[7]=fb.w;
            f[8]=fc2.x; f[9]=fc2.y;
            #pragma unroll
            for (int k = 0; k < 3; ++k) {
                const float* wrow = &Ws[c * 3 + k][o0];
                float4 wa = *(const float4*)&wrow[0];
                float4 wb = *(const float4*)&wrow[4];
                float w[8] = {wa.x, wa.y, wa.z, wa.w, wb.x, wb.y, wb.z, wb.w};
                #pragma unroll
                for (int oi = 0; oi < 8; ++oi)
                    #pragma unroll
                    for (int li = 0; li < 8; ++li)
                        acc[oi][li] = fmaf(w[oi], f[li + k], acc[oi][li]);
            }
        }
    }
    const int mflag = mflag_p[0];
    const int lbase = l0 + ll;
    float mv[8];
    #pragma unroll
    for (int li = 0; li < 8; ++li) {
        int idx = b * L_ + lbase + li;
        if (mflag == 1)      mv[li] = mask[idx] ? 1.f : 0.f;
        else if (mflag == 0) mv[li] = ((const int*)mask)[idx] ? 1.f : 0.f;
        else                 mv[li] = ((const int*)mask)[2 * idx] ? 1.f : 0.f;
    }
    #pragma unroll
    for (int oi = 0; oi < 8; ++oi) {
        float bo = bias[o0 + oi];
        float* dst = out + ((size_t)b * O_ + o0 + oi) * L_ + lbase;
        #pragma unroll
        for (int li = 0; li < 8; ++li) dst[li] = (acc[oi][li] + bo) * mv[li];
    }
}

extern "C" void kernel_launch(void* const* d_in, const int* in_sizes, int n_in,
                              void* d_out, int out_size, void* d_ws, size_t ws_size,
                              hipStream_t stream) {
    const float*         inputs = (const float*)d_in[0];
    const int*           conn   = (const int*)d_in[1];
    const unsigned char* mask   = (const unsigned char*)d_in[2];
    const float*         W      = (const float*)d_in[3];
    const float*         bias   = (const float*)d_in[4];
    float*               out    = (float*)d_out;

    const size_t g_bytes  = G_ELEMS * sizeof(_Float16);    // 37.75 MB
    const size_t wt_bytes = WT_ELEMS * sizeof(_Float16);   // 221 KB
    const size_t need     = g_bytes + wt_bytes + 64;

    if (ws_size < need) {
        int* mflag = (int*)d_ws;
        detect_kernel<<<1, 256, 0, stream>>>((const uint4*)mask, mflag);
        dim3 grid(L_ / 128, B_);
        cc_fallback_kernel<<<grid, 256, 0, stream>>>(inputs, conn, mask, W, bias, out, mflag);
        return;
    }

    _Float16* G     = (_Float16*)d_ws;
    _Float16* Wt2   = (_Float16*)((char*)d_ws + g_bytes);
    int*      mflag = (int*)((char*)d_ws + g_bytes + wt_bytes);

    prep_kernel<<<2481, 256, 0, stream>>>(inputs, W, (const uint4*)mask, G, Wt2, mflag);
    k1_gather_penc<<<1024, 256, 0, stream>>>(conn, G);
    k2_gemm<<<256, 256, 0, stream>>>(G, Wt2, mask, bias, out, mflag);
}

// Round 24
// 42.484 us; speedup vs baseline: 1.1339x; 1.1339x over previous
//
#include <hip/hip_runtime.h>
#include <math.h>

#define B_    8
#define C_    128
#define L_    8192
#define O_    128
#define POS_  10
#define CHIN  798
#define CH_   266          // 128 direct + 128 gathered + 10 penc
#define GS    288          // G row stride (all channels materialized)
#define NCH   9            // chunks of 32 channels
#define TL2   128          // l-tile for GEMM (512 blocks -> 3 blocks/CU by LDS)
#define G_ELEMS  ((size_t)B_ * L_ * GS)       // f16: 37.75 MB
#define WT_ELEMS ((size_t)3 * NCH * O_ * 32)  // f16: 221 KB

typedef _Float16 half8 __attribute__((ext_vector_type(8)));
typedef short short8 __attribute__((ext_vector_type(8)));
typedef float f32x4  __attribute__((ext_vector_type(4)));

typedef __attribute__((address_space(3))) unsigned       lds_uint;
typedef __attribute__((address_space(1))) const unsigned gl_uint;

// direct global->LDS DMA, 16B per lane; LDS dest is wave-uniform base + lane*16
__device__ __forceinline__ void dma16(const _Float16* g, _Float16* l) {
    __builtin_amdgcn_global_load_lds((gl_uint*)g, (lds_uint*)l, 16, 0, 0);
}

// ---------------------------------------------------------------------------
// mask dtype detect core: 256 threads scan 64 KB; mflag 1=byte,0=i32,2=i64
// ---------------------------------------------------------------------------
__device__ __forceinline__ void detect_core(const uint4* __restrict__ m,
                                            int* __restrict__ mflag, int tid) {
    __shared__ int s[2];
    if (tid < 2) s[tid] = 0;
    __syncthreads();
    unsigned sub = 0, mid = 0;
    #pragma unroll
    for (int k = 0; k < 16; ++k) {
        uint4 w = m[tid + k * 256];              // 4096 * 16B = 64 KB
        sub |= (w.x | w.y | w.z | w.w) & 0xFFFFFF00u;
        mid |= (w.y | w.w) & 0x000000FFu;
    }
    unsigned long long bs = __ballot(sub != 0);
    unsigned long long bm = __ballot(mid != 0);
    if ((tid & 63) == 0) {
        if (bs) atomicOr(&s[0], 1);
        if (bm) atomicOr(&s[1], 1);
    }
    __syncthreads();
    if (tid == 0) mflag[0] = s[0] ? 1 : (s[1] ? 0 : 2);
}

__global__ void detect_kernel(const uint4* __restrict__ m, int* __restrict__ mflag) {
    detect_core(m, mflag, threadIdx.x);
}

// ---------------------------------------------------------------------------
// prep: blocks [0,2048): transpose inputs[b,c,l] f32 -> G[b,l,c] f16 (c<128)
//       blocks [2048,2480): Wt2[t][ch][o][cc] = (f16) W[o][3*(ch*32+cc)+t]
//       block 2480: mask dtype detect
// ---------------------------------------------------------------------------
__global__ __launch_bounds__(256, 4)
void prep_kernel(const float* __restrict__ inputs, const float* __restrict__ W,
                 const uint4* __restrict__ maskv,
                 _Float16* __restrict__ G, _Float16* __restrict__ Wt2,
                 int* __restrict__ mflag) {
    __shared__ float tile[64][65];
    const int bid = blockIdx.x;
    const int tid = threadIdx.x;

    if (bid == 2480) { detect_core(maskv, mflag, tid); return; }

    if (bid >= 2048) {   // Wt2 prep: 432 blocks * 256 = 110,592 elems exact
        int idx = (bid - 2048) * 256 + tid;
        int cc  = idx & 31;
        int o   = (idx >> 5) & 127;
        int tch = idx >> 12;          // 0..26
        int ch  = tch % 9;
        int t   = tch / 9;
        int cg  = ch * 32 + cc;
        Wt2[idx] = (cg < CH_) ? (_Float16)W[o * CHIN + 3 * cg + t] : (_Float16)0.f;
        return;
    }

    const int b  = bid & 7;          // b -> XCD affinity
    const int r  = bid >> 3;
    const int c0 = (r & 1) * 64;
    const int l0 = (r >> 1) * 64;
    const int ty = tid >> 6, tx = tid & 63;

    #pragma unroll
    for (int it = 0; it < 16; ++it) {
        int cl = it * 4 + ty;
        tile[cl][tx] = inputs[((size_t)(b * C_ + c0 + cl)) * L_ + l0 + tx];
    }
    __syncthreads();
    const int cp = (tid & 31) * 2;
    const int lr = tid >> 5;          // 0..7
    #pragma unroll
    for (int it = 0; it < 8; ++it) {
        int ll = it * 8 + lr;
        _Float16 pair[2] = {(_Float16)tile[cp][ll], (_Float16)tile[cp + 1][ll]};
        *(unsigned*)&G[((size_t)(b * L_ + l0 + ll)) * GS + c0 + cp] = *(unsigned*)pair;
    }
}

// ---------------------------------------------------------------------------
// K1: gather + penc into G (coalesced; uint4/lane -> 256B per 16-lane row):
//   G[b,l,128+c] = G[b,conn[b,l],c]  (c<128) ; G[b,l,256+p] = penc (p<32)
// ---------------------------------------------------------------------------
__global__ __launch_bounds__(256, 4)
void k1_gather_penc(const int* __restrict__ conn, _Float16* __restrict__ G) {
    const int bid = blockIdx.x;
    const int b  = bid & 7;
    const int l0 = (bid >> 3) * 64;
    const int tid = threadIdx.x;
    const int wv = tid >> 6, lane = tid & 63;

    // gather: 4 rows per wave-iter; 16B/lane x 16 lanes = 256B per row
    #pragma unroll
    for (int i = 0; i < 4; ++i) {
        int l  = l0 + wv * 16 + i * 4 + (lane >> 4);
        int cj = conn[b * L_ + l];
        uint4 v = *(const uint4*)&G[((size_t)(b * L_ + cj)) * GS + (lane & 15) * 8];
        *(uint4*)&G[((size_t)(b * L_ + l)) * GS + 128 + (lane & 15) * 8] = v;
    }

    // penc: thread -> (l, 8-wide c' group); channels 256..287 (zeros past 265)
    {
        int l = l0 + (tid >> 2);
        int s = tid & 3;
        int cj = conn[b * L_ + l];
        float d = (float)(l - cj);
        _Float16 v[8];
        #pragma unroll
        for (int e = 0; e < 8; ++e) {
            int p = s * 8 + e;
            if (p < POS_) {
                float sc = (float)(1 << p);
                v[e] = (_Float16)sinf((sc * d) / 1000.0f);
            } else v[e] = (_Float16)0.f;
        }
        *(short8*)&G[((size_t)(b * L_ + l)) * GS + 256 + s * 8] = *(short8*)v;
    }
}

// ---------------------------------------------------------------------------
// K2: f16 MFMA GEMM, all-contiguous global_load_lds staging (R22-best config).
// LDS 41.2 KB -> 3 blocks/CU resident: A SINGLE-buffered (identical across
// blocks; its per-chunk reload latency is hidden by co-resident blocks),
// B double-buffered (DMA overlaps compute). 2 barriers/chunk.
// grid 512 flat (b=bid&7 -> XCD). 256 thr = 4 waves (2o x 2l), wave 64o x 64l.
// ---------------------------------------------------------------------------
__global__ __launch_bounds__(256)
void k2_gemm(const _Float16* __restrict__ G, const _Float16* __restrict__ Wt2,
             const unsigned char* __restrict__ mask,
             const float* __restrict__ bias,
             float* __restrict__ out,
             const int* __restrict__ mflag_p) {
    __shared__ _Float16 As[3][128][32];     // 24.6 KB [tap][o][c] single buffer
    __shared__ _Float16 Bs[2][130][32];     // 16.3 KB [buf][row][c]

    const int bid = blockIdx.x;           // 0..511
    const int b   = bid & 7;
    const int l0  = (bid >> 3) * TL2;
    const int tid  = threadIdx.x;
    const int wave = tid >> 6;            // 0..3
    const int lane = tid & 63;
    const int wo = wave & 1;
    const int wl = wave >> 1;
    const int g  = lane >> 4;
    const int ln = lane & 15;

    const _Float16* gb = G + (size_t)b * L_ * GS;
    const int cbl = lane & 3;             // 16B slot within 64B row segment

    auto stage_A = [&](int ch) {
        #pragma unroll
        for (int i = 0; i < 6; ++i) {
            int ap = 6 * wave + i;        // 0..23
            int tp = ap >> 3;             // 0..2
            int og = ap & 7;              // o block of 16
            int o  = og * 16 + (lane >> 2);
            dma16(&Wt2[((size_t)((tp * NCH + ch) * O_ + o)) * 32 + cbl * 8],
                  &As[tp][og * 16][0]);
        }
    };
    auto stage_B = [&](int ch, int buf) {
        #pragma unroll
        for (int i = 0; i < 2; ++i) {
            int r0 = 1 + 32 * wave + 16 * i;
            int r  = r0 + (lane >> 2);    // rows 1..128 -> l in [l0, l0+127]
            dma16(&gb[(size_t)(l0 - 1 + r) * GS + ch * 32 + cbl * 8],
                  &Bs[buf][r0][0]);
        }
    };

    // halo rows 0 and 129 (l = l0-1, l0+128): 8 threads reg-stage
    auto halo_load = [&](int ch) -> short8 {
        int row = (tid >> 2) ? 129 : 0;
        int l_  = l0 - 1 + row;
        short8 v = (short8)0;
        if ((unsigned)l_ < (unsigned)L_)
            v = *(const short8*)&gb[(size_t)l_ * GS + ch * 32 + (tid & 3) * 8];
        return v;
    };
    auto halo_write = [&](short8 v, int buf) {
        int row = (tid >> 2) ? 129 : 0;
        *(short8*)&Bs[buf][row][(tid & 3) * 8] = v;
    };

#define COMPUTE(BUF) { _Pragma("unroll") for (int t_ = 0; t_ < 3; ++t_) { \
        half8 bf_[4]; \
        _Pragma("unroll") for (int n_ = 0; n_ < 4; ++n_) \
            bf_[n_] = *(const half8*)&Bs[BUF][wl * 64 + n_ * 16 + ln + t_][8 * g]; \
        _Pragma("unroll") for (int m_ = 0; m_ < 4; ++m_) { \
            half8 af_ = *(const half8*)&As[t_][wo * 64 + m_ * 16 + ln][8 * g]; \
            _Pragma("unroll") for (int n_ = 0; n_ < 4; ++n_) \
                acc[m_][n_] = __builtin_amdgcn_mfma_f32_16x16x32_f16(af_, bf_[n_], acc[m_][n_], 0, 0, 0); } } }

    f32x4 acc[4][4];
    #pragma unroll
    for (int m = 0; m < 4; ++m)
        #pragma unroll
        for (int n = 0; n < 4; ++n) acc[m][n] = (f32x4)0.f;

    short8 hv;

    // prologue: stage chunk 0 (A + B into buf 0)
    stage_A(0);
    stage_B(0, 0);
    if (tid < 8) { hv = halo_load(0); halo_write(hv, 0); }
    __syncthreads();   // vmcnt(0) drain before barrier

    int cur = 0;
    for (int ch = 0; ch < NCH; ++ch) {
        const bool more = (ch + 1 < NCH);
        if (more) {
            stage_B(ch + 1, cur ^ 1);      // overlaps with compute below
            if (tid < 8) hv = halo_load(ch + 1);
        }
        COMPUTE(cur);
        if (more) {
            __syncthreads();               // all waves done reading As
            stage_A(ch + 1);               // single-buffer A reload
            if (tid < 8) halo_write(hv, cur ^ 1);
            __syncthreads();               // drain A-DMA; publish halo
            cur ^= 1;
        }
    }

    // epilogue: D col = lane&15 (l), row = g*4+r (o) within frag
    const int mflag = mflag_p[0];
    float mv[4];
    #pragma unroll
    for (int n = 0; n < 4; ++n) {
        int l = l0 + wl * 64 + n * 16 + ln;
        int idx = b * L_ + l;
        if (mflag == 1)      mv[n] = mask[idx] ? 1.f : 0.f;
        else if (mflag == 0) mv[n] = ((const int*)mask)[idx] ? 1.f : 0.f;
        else                 mv[n] = ((const int*)mask)[2 * idx] ? 1.f : 0.f;
    }
    #pragma unroll
    for (int m = 0; m < 4; ++m) {
        #pragma unroll
        for (int r = 0; r < 4; ++r) {
            int o = wo * 64 + m * 16 + g * 4 + r;
            float bo = bias[o];
            #pragma unroll
            for (int n = 0; n < 4; ++n) {
                int l = l0 + wl * 64 + n * 16 + ln;
                out[((size_t)(b * O_ + o)) * L_ + l] = (acc[m][n][r] + bo) * mv[n];
            }
        }
    }
#undef COMPUTE
}

// ---------------------------------------------------------------------------
// Fallback (fp32 vector path) if workspace too small
// ---------------------------------------------------------------------------
__global__ __launch_bounds__(256, 2)
void cc_fallback_kernel(const float* __restrict__ inputs,
                        const int* __restrict__ conn,
                        const unsigned char* __restrict__ mask,
                        const float* __restrict__ W,
                        const float* __restrict__ bias,
                        float* __restrict__ out,
                        const int* __restrict__ mflag_p) {
    __shared__ int   conn_s[130];
    __shared__ float feat_s[16][132];
    __shared__ float Ws[48][136];

    const int b   = blockIdx.y;
    const int l0  = blockIdx.x * 128;
    const int tid = threadIdx.x;
    const int ot  = tid >> 4;
    const int lt  = tid & 15;
    const int o0  = ot * 8;
    const int ll  = lt * 8;

    for (int j = tid; j < 130; j += 256) {
        int lg = l0 - 1 + j;
        conn_s[j] = ((unsigned)lg < (unsigned)L_) ? conn[b * L_ + lg] : -1;
    }
    float acc[8][8];
    #pragma unroll
    for (int i = 0; i < 8; ++i)
        #pragma unroll
        for (int j = 0; j < 8; ++j) acc[i][j] = 0.f;

    const int tc = ot, tj = lt;
    for (int chunk = 0; chunk < 17; ++chunk) {
        const int CN  = (chunk < 16) ? 16 : POS_;
        const int cg0 = chunk * 16;
        const int col0 = 3 * cg0;
        __syncthreads();
        {
            const int nw = O_ * CN * 3;
            for (int idx = tid; idx < nw; idx += 256) {
                int o = idx & 127, kk = idx >> 7;
                Ws[kk][o] = W[o * CHIN + col0 + kk];
            }
        }
        if (chunk < 8) {
            const float* src = inputs + ((size_t)b * C_ + (cg0 + tc)) * L_;
            for (int j = tj; j < 130; j += 16) {
                int lg = l0 - 1 + j;
                feat_s[tc][j] = ((unsigned)lg < (unsigned)L_) ? src[lg] : 0.f;
            }
        } else if (chunk < 16) {
            const float* src = inputs + ((size_t)b * C_ + (cg0 - 128 + tc)) * L_;
            for (int j = tj; j < 130; j += 16) {
                int cj = conn_s[j];
                feat_s[tc][j] = (cj >= 0) ? src[cj] : 0.f;
            }
        } else if (tc < POS_) {
            const float sc = (float)(1 << tc);
            for (int j = tj; j < 130; j += 16) {
                int cj = conn_s[j];
                int lg = l0 - 1 + j;
                float v = 0.f;
                if (cj >= 0) v = sinf((sc * (float)(lg - cj)) / 1000.0f);
                feat_s[tc][j] = v;
            }
        }
        __syncthreads();
        for (int c = 0; c < CN; ++c) {
            float f[10];
            float4 fa = *(const float4*)&feat_s[c][ll];
            float4 fb = *(const float4*)&feat_s[c][ll + 4];
            float2 fc2 = *(const float2*)&feat_s[c][ll + 8];
            f[0]=fa.x; f[1]=fa.y; f[2]=fa.z; f[3]=fa.w;
            f[4]=fb.x; f[5]=fb.y; f[6]=fb.z; f[7]=fb.w;
            f[8]=fc2.x; f[9]=fc2.y;
            #pragma unroll
            for (int k = 0; k < 3; ++k) {
                const float* wrow = &Ws[c * 3 + k][o0];
                float4 wa = *(const float4*)&wrow[0];
                float4 wb = *(const float4*)&wrow[4];
                float w[8] = {wa.x, wa.y, wa.z, wa.w, wb.x, wb.y, wb.z, wb.w};
                #pragma unroll
                for (int oi = 0; oi < 8; ++oi)
                    #pragma unroll
                    for (int li = 0; li < 8; ++li)
                        acc[oi][li] = fmaf(w[oi], f[li + k], acc[oi][li]);
            }
        }
    }
    const int mflag = mflag_p[0];
    const int lbase = l0 + ll;
    float mv[8];
    #pragma unroll
    for (int li = 0; li < 8; ++li) {
        int idx = b * L_ + lbase + li;
        if (mflag == 1)      mv[li] = mask[idx] ? 1.f : 0.f;
        else if (mflag == 0) mv[li] = ((const int*)mask)[idx] ? 1.f : 0.f;
        else                 mv[li] = ((const int*)mask)[2 * idx] ? 1.f : 0.f;
    }
    #pragma unroll
    for (int oi = 0; oi < 8; ++oi) {
        float bo = bias[o0 + oi];
        float* dst = out + ((size_t)b * O_ + o0 + oi) * L_ + lbase;
        #pragma unroll
        for (int li = 0; li < 8; ++li) dst[li] = (acc[oi][li] + bo) * mv[li];
    }
}

extern "C" void kernel_launch(void* const* d_in, const int* in_sizes, int n_in,
                              void* d_out, int out_size, void* d_ws, size_t ws_size,
                              hipStream_t stream) {
    const float*         inputs = (const float*)d_in[0];
    const int*           conn   = (const int*)d_in[1];
    const unsigned char* mask   = (const unsigned char*)d_in[2];
    const float*         W      = (const float*)d_in[3];
    const float*         bias   = (const float*)d_in[4];
    float*               out    = (float*)d_out;

    const size_t g_bytes  = G_ELEMS * sizeof(_Float16);    // 37.75 MB
    const size_t wt_bytes = WT_ELEMS * sizeof(_Float16);   // 221 KB
    const size_t need     = g_bytes + wt_bytes + 64;

    if (ws_size < need) {
        int* mflag = (int*)d_ws;
        detect_kernel<<<1, 256, 0, stream>>>((const uint4*)mask, mflag);
        dim3 grid(L_ / 128, B_);
        cc_fallback_kernel<<<grid, 256, 0, stream>>>(inputs, conn, mask, W, bias, out, mflag);
        return;
    }

    _Float16* G     = (_Float16*)d_ws;
    _Float16* Wt2   = (_Float16*)((char*)d_ws + g_bytes);
    int*      mflag = (int*)((char*)d_ws + g_bytes + wt_bytes);

    prep_kernel<<<2481, 256, 0, stream>>>(inputs, W, (const uint4*)mask, G, Wt2, mflag);
    k1_gather_penc<<<1024, 256, 0, stream>>>(conn, G);
    k2_gemm<<<512, 256, 0, stream>>>(G, Wt2, mask, bias, out, mflag);
}